// Round 2
// baseline (55.506 us; speedup 1.0000x reference)
//
#include <hip/hip_runtime.h>
#include <math.h>

#define NQ     12
#define DIM    4096
#define DEPTH  6
#define NBATCH 256

// ---------------------------------------------------------------------------
// Algebra: CNOT-ladder perm is the Gray map g(j) = j ^ (j>>1), linear on GF(2)^12.
// Never permute the stored state. Depth-d gates on logical bit b become
// butterflies on XOR-axis  V = A^d e_b  with role selector = row b of A^{-d},
// where A(m) = m ^ (m>>1). Since S^12 = 0, A^16 = I, so A^{-d} = A^{16-d}.
// Observables (logical bits 11,10,9 after 6 perms) reduce to stored-index
// parity masks 0x800, 0x400, 0xA00 — i.e. lane bits only.
// Layout: stored index j = (lane << 6) | reg, one wave per batch element,
// 64 f32 state registers per lane. 36 gates are pure-register butterflies,
// 36 are one shfl_xor per element. No LDS, no barriers.
// ---------------------------------------------------------------------------

__host__ __device__ constexpr unsigned axmask(int d, int b) {
    unsigned m = 1u << b;
    for (int i = 0; i < d; ++i) m = (m ^ (m >> 1)) & 0xFFFu;
    return m;
}
__host__ __device__ constexpr unsigned selmask(int d, int b) {
    // row b of A^{-d} = (A^T)^{16-d} applied to e_b;  A^T(m) = m ^ (m<<1)
    unsigned m = 1u << b;
    for (int i = 0; i < 16 - d; ++i) m = (m ^ ((m << 1) & 0xFFFu)) & 0xFFFu;
    return m;
}

template<int D, int B>
__device__ __forceinline__ void apply_gate(float (&st)[64], float c, float s, int lane) {
    constexpr unsigned V  = axmask(D, B);
    constexpr unsigned M  = selmask(D, B);
    constexpr int VH = (int)(V >> 6), VL = (int)(V & 63u);
    constexpr unsigned MH = M >> 6, ML = M & 63u;

    // lane part of selector parity; s_eff for reg-parity==0 elements
    float sp = (__popc(MH & (unsigned)lane) & 1) ? s : -s;

    if constexpr (VH == 0) {
        // pure-register butterfly: pairs (r, r^VL)
        #pragma unroll
        for (int r = 0; r < 64; ++r) {
            if ((r ^ VL) > r) {
                const int r2 = r ^ VL;
                float a0 = st[r], a1 = st[r2];
                float se0 = (__popc(ML & (unsigned)r)  & 1) ? -sp : sp;
                float se1 = (__popc(ML & (unsigned)r2) & 1) ? -sp : sp;
                st[r]  = fmaf(c, a0, se0 * a1);
                st[r2] = fmaf(c, a1, se1 * a0);
            }
        }
    } else {
        // lane-crossing butterfly: partner = (lane^VH, r^VL) via shfl_xor
        float pr[64];
        #pragma unroll
        for (int r = 0; r < 64; ++r)
            pr[r] = __shfl_xor(st[r ^ VL], VH, 64);
        #pragma unroll
        for (int r = 0; r < 64; ++r) {
            float se = (__popc(ML & (unsigned)r) & 1) ? -sp : sp;
            st[r] = fmaf(c, st[r], se * pr[r]);
        }
    }
}

__global__ void prep_kernel(const float* __restrict__ thetas, float2* __restrict__ cs) {
    int t = threadIdx.x;
    if (t < DEPTH * NQ) {
        float h = thetas[t] * 0.5f;
        cs[t] = make_float2(cosf(h), sinf(h));
    }
}

__global__ __launch_bounds__(64, 1)
void qnet_kernel(const float* __restrict__ x,      // [NBATCH, NQ]
                 const float2* __restrict__ cs,    // [DEPTH*NQ] (cos,sin)
                 float* __restrict__ out)          // [NBATCH, 3]
{
    const int b    = blockIdx.x;
    const int lane = threadIdx.x;   // 0..63

    // ---- encoder trig (uniform per wave except lane products) ----
    float cq[12], sq[12];
    #pragma unroll
    for (int q = 0; q < 12; ++q) {
        float h = x[b * 12 + q] * 1.57079632679489662f;  // pi/2 * x
        sq[q] = sinf(h);
        cq[q] = cosf(h);
    }

    // ---- product state: st[r] for j = (lane<<6)|r ----
    // j bit (6+i) = lane bit i  <-> qubit 5-i ; j bit i = reg bit i <-> qubit 11-i
    float la = 1.0f;
    #pragma unroll
    for (int i = 0; i < 6; ++i)
        la *= ((lane >> i) & 1) ? sq[5 - i] : cq[5 - i];

    float st[64];
    st[0] = la;
    #pragma unroll
    for (int i = 0; i < 6; ++i) {
        #pragma unroll
        for (int k = 0; k < (1 << i); ++k) {
            float base = st[k];
            st[k + (1 << i)] = base * sq[11 - i];
            st[k]            = base * cq[11 - i];
        }
    }

    // ---- 6 depths x 12 gates, all in registers/shuffles ----
    // gate for qubit Q at depth D acts on logical bit 11-Q, theta cs[D*12+Q]
    #define GATE(D, Q) do { float2 cs_ = cs[(D)*12 + (Q)]; \
                            apply_gate<D, 11-(Q)>(st, cs_.x, cs_.y, lane); } while (0)
    #define DEPTH_GATES(D) \
        GATE(D,0); GATE(D,1); GATE(D,2);  GATE(D,3);  GATE(D,4);  GATE(D,5); \
        GATE(D,6); GATE(D,7); GATE(D,8);  GATE(D,9);  GATE(D,10); GATE(D,11)
    DEPTH_GATES(0);
    DEPTH_GATES(1);
    DEPTH_GATES(2);
    DEPTH_GATES(3);
    DEPTH_GATES(4);
    DEPTH_GATES(5);
    #undef DEPTH_GATES
    #undef GATE

    // ---- observer ----
    // sign masks on stored index: q0 -> bit11 (lane b5), q1 -> bit10 (lane b4),
    // q2 -> bits 9^11 (lane b3 ^ b5). Per-lane probability sum first.
    float tot = 0.0f;
    #pragma unroll
    for (int r = 0; r < 64; ++r)
        tot = fmaf(st[r], st[r], tot);

    float a0 = ((lane >> 5) & 1)                ? -tot : tot;
    float a1 = ((lane >> 4) & 1)                ? -tot : tot;
    float a2 = (((lane >> 3) ^ (lane >> 5)) & 1) ? -tot : tot;

    #pragma unroll
    for (int off = 32; off; off >>= 1) {
        a0 += __shfl_xor(a0, off, 64);
        a1 += __shfl_xor(a1, off, 64);
        a2 += __shfl_xor(a2, off, 64);
    }
    if (lane == 0) {
        out[b * 3 + 0] = a0;
        out[b * 3 + 1] = a1;
        out[b * 3 + 2] = a2;
    }
}

extern "C" void kernel_launch(void* const* d_in, const int* in_sizes, int n_in,
                              void* d_out, int out_size, void* d_ws, size_t ws_size,
                              hipStream_t stream) {
    (void)in_sizes; (void)n_in; (void)out_size; (void)ws_size;
    const float* x      = (const float*)d_in[0];   // [256,12] f32
    const float* thetas = (const float*)d_in[1];   // [6,12]   f32
    float* out          = (float*)d_out;           // [256,3]  f32
    float2* cs          = (float2*)d_ws;           // 72 * 8B scratch

    prep_kernel<<<dim3(1), dim3(128), 0, stream>>>(thetas, cs);
    qnet_kernel<<<dim3(NBATCH), dim3(64), 0, stream>>>(x, cs, out);
}